// Round 8
// baseline (233.174 us; speedup 1.0000x reference)
//
#include <hip/hip_runtime.h>

// KappaGCN layer on MI355X. KAPPA=-1, N=8192, D=512.
// Round 8: occupancy + phase split. R7 analysis: per-K-step LDS frag reads
// (~1500 cyc) + staging + MFMA never overlap in a lockstep 1-block/CU loop.
// Now: 128x256 tile, 256 thr (4 waves 2x2, wave tile 64x128), LDS 72 KB ->
// 2 blocks/CU; split-K=2; per K-step 2 phases {reads+16 MFMA} {stage+16 MFMA}
// with setprio(1) around MFMA clusters and counted vmcnt(8) once per step.
// fp32 A staged via global_load_lds with slot^(row&7) swizzle (pre-swizzled
// source); denom/alpha fused as extra MFMAs vs {g1bf,1} on wn==0 waves.

#define NR 8192
#define DD 512

typedef unsigned int u32;
typedef unsigned short u16;
typedef __attribute__((ext_vector_type(8))) short bf16x8;
typedef __attribute__((ext_vector_type(4))) float f32x4;

__device__ __forceinline__ u16 f2bf(float f) {
  u32 u = __float_as_uint(f);
  u32 r = u + 0x7FFFu + ((u >> 16) & 1u);   // round-to-nearest-even
  return (u16)(r >> 16);
}

__device__ __forceinline__ u32 cvtpk(float lo, float hi) {
  u32 r;
  asm("v_cvt_pk_bf16_f32 %0, %1, %2" : "=v"(r) : "v"(lo), "v"(hi));
  return r;
}

__device__ __forceinline__ void gload16(const void* g, void* l) {
  __builtin_amdgcn_global_load_lds(
      (const __attribute__((address_space(1))) u32*)g,
      (__attribute__((address_space(3))) u32*)l, 16, 0, 0);
}

__device__ __forceinline__ float wred(float v) {
  #pragma unroll
  for (int off = 32; off; off >>= 1) v += __shfl_xor(v, off, 64);
  return v;
}

// W [K=512][N=512] fp32 -> Wt [N][K] bf16, 16B-slot swizzled per 32-k chunk
__global__ __launch_bounds__(256) void conv_wt(const float* __restrict__ W,
                                               u16* __restrict__ Wt) {
  const int idx = blockIdx.x * 256 + threadIdx.x;  // 0..32767
  const int n  = idx >> 6;
  const int k0 = (idx & 63) * 8;
  u32 r[4];
  #pragma unroll
  for (int j = 0; j < 4; ++j) {
    float lo = W[(size_t)(k0 + 2*j    ) * DD + n];
    float hi = W[(size_t)(k0 + 2*j + 1) * DD + n];
    r[j] = (u32)f2bf(lo) | ((u32)f2bf(hi) << 16);
  }
  const int dst = n * DD + ((idx & 63) >> 2) * 32 + (((idx & 3) ^ (n & 3)) * 8);
  *(uint4*)(Wt + dst) = *(const uint4*)r;
}

// ---------------- GEMM: C[M][512] = Af[M][K](fp32) * Bt[512][K](bf16,swz) --
// 128x256 tile, BK=32, 4 waves (2x2), wave tile 64x128 (4x8 frags 16x16x32).
// 2 blocks/CU. Per K-step: Ph0 {16 frag reads, prio MFMA x16}, barrier,
// Ph1 {stage 8 gload_lds, prio MFMA x16 + dosum}, vmcnt(8), barrier.
template <int DOSUM>
__global__ __launch_bounds__(256, 2) void gemm_ph(
    const float* __restrict__ Af, const u16* __restrict__ Bt,
    const u16* __restrict__ g1bf,
    float* __restrict__ C0, float* __restrict__ Cext,
    float* __restrict__ denp, float* __restrict__ alp,
    int M, int K, int kchunk, int nkc) {
  __shared__ __align__(16) float ldsA[2][4096];   // [128][32] f32, slot^row&7
  __shared__ __align__(16) u16   ldsB[2][8192];   // [256][32] bf16, slot^row&3
  __shared__ __align__(16) u16   ldsG[4096];      // g1bf chunk (DOSUM)

  // decode: nt = bid&1 (N half), kc from next bit(s), mt the rest.
  // XCD (bid%8) fixes (nt,kc) -> 2 MB B-chunk L2-resident per XCD.
  const int bid = blockIdx.x;
  const int nt = bid & 1;
  const int h  = bid >> 1;
  const int kc = (nkc == 2) ? (h & 1) : 0;
  const int mt = (nkc == 2) ? (h >> 1) : h;

  const int t = threadIdx.x;
  const int lane = t & 63, w = t >> 6;
  const int wm = w >> 1, wn = w & 1;              // 2 x 2 waves
  const int m0 = mt * 128, n0 = nt * 256;
  const int kbeg = kc * kchunk;
  const int lr = lane & 15, lk = lane >> 4, lx = lr & 7;
  const bool doRS = DOSUM && (nt == 0);

  // A staging: thread t covers rows (t>>3)+32j, phys slot t&7;
  // source fetches logical slot (t&7)^(row&7) (pre-swizzle).
  const int scol = ((t & 7) ^ ((t >> 3) & 7)) << 2;   // floats
  const float* gA0 = Af + (size_t)(m0 + (t >> 3)) * K + kbeg + scol;
  // B staging (verbatim; Bt pre-swizzled in global): rows (t>>2)+64j
  const u16* gB = Bt + (size_t)(n0 + (t >> 2)) * K + kbeg + (t & 3) * 8;

  auto stage = [&](int buf, int kt) {
    const int ko = kt * 32;
    #pragma unroll
    for (int j = 0; j < 4; ++j)
      gload16(gA0 + ko + (size_t)j * 32 * K, &ldsA[buf][t * 4 + j * 1024]);
    #pragma unroll
    for (int j = 0; j < 4; ++j)
      gload16(gB + ko + (size_t)j * 64 * K, &ldsB[buf][t * 8 + j * 2048]);
  };

  f32x4 acc[4][8];
  #pragma unroll
  for (int i = 0; i < 4; ++i)
    #pragma unroll
    for (int j = 0; j < 8; ++j) acc[i][j] = (f32x4){0.f, 0.f, 0.f, 0.f};
  f32x4 accS[4];
  #pragma unroll
  for (int i = 0; i < 4; ++i) accS[i] = (f32x4){0.f, 0.f, 0.f, 0.f};

  const int nT = kchunk / 32;

  // ---- prologue: ldsG + tiles 0,1; wait tile 0 only ----
  if (doRS) {
    #pragma unroll
    for (int j = 0; j < 2; ++j)
      gload16(g1bf + kbeg + t * 8 + j * 2048, &ldsG[t * 8 + j * 2048]);
  }
  stage(0, 0);
  stage(1, 1);
  asm volatile("s_waitcnt vmcnt(8)" ::: "memory");
  __builtin_amdgcn_s_barrier();
  __builtin_amdgcn_sched_barrier(0);

  int cur = 0;
  for (int tt = 0; tt < nT; ++tt) {
    // ---- Ph0: all frag reads from buf[cur], then first MFMA cluster ----
    bf16x8 af[4], bv[8];
    #pragma unroll
    for (int i = 0; i < 4; ++i) {
      const int rbase = (wm * 64 + i * 16 + lr) * 32;
      f32x4 lo = *(const f32x4*)&ldsA[cur][rbase + (((2*lk    ) ^ lx) << 2)];
      f32x4 hi = *(const f32x4*)&ldsA[cur][rbase + (((2*lk + 1) ^ lx) << 2)];
      union { u32 u[4]; bf16x8 v; } pk;
      pk.u[0] = cvtpk(lo.x, lo.y); pk.u[1] = cvtpk(lo.z, lo.w);
      pk.u[2] = cvtpk(hi.x, hi.y); pk.u[3] = cvtpk(hi.z, hi.w);
      af[i] = pk.v;
    }
    #pragma unroll
    for (int i = 0; i < 8; ++i) {
      const int rb = (wn * 128 + i * 16 + lr) * 32 + ((lk ^ (lr & 3)) << 3);
      bv[i] = *(const bf16x8*)&ldsB[cur][rb];
    }
    __builtin_amdgcn_s_setprio(1);
    #pragma unroll
    for (int mi = 0; mi < 4; ++mi)
      #pragma unroll
      for (int ni = 0; ni < 4; ++ni)
        acc[mi][ni] = __builtin_amdgcn_mfma_f32_16x16x32_bf16(
            af[mi], bv[ni], acc[mi][ni], 0, 0, 0);
    __builtin_amdgcn_s_setprio(0);
    // all this wave's reads of buf[cur] done before anyone stages into it
    asm volatile("s_waitcnt lgkmcnt(0)" ::: "memory");
    __builtin_amdgcn_sched_barrier(0);
    __builtin_amdgcn_s_barrier();
    __builtin_amdgcn_sched_barrier(0);
    // ---- Ph1: stage tt+2 into buf[cur], second MFMA cluster ----
    if (tt + 2 < nT) stage(cur, tt + 2);
    bf16x8 gv;
    if (doRS && wn == 0) {
      if (lr == 0) {
        gv = *(const bf16x8*)&ldsG[tt * 32 + lk * 8];
      } else {
        const short s = (lr == 1) ? (short)0x3F80 : (short)0;
        gv = (bf16x8){s, s, s, s, s, s, s, s};
      }
    }
    __builtin_amdgcn_sched_barrier(0);
    __builtin_amdgcn_s_setprio(1);
    #pragma unroll
    for (int mi = 0; mi < 4; ++mi)
      #pragma unroll
      for (int ni = 4; ni < 8; ++ni)
        acc[mi][ni] = __builtin_amdgcn_mfma_f32_16x16x32_bf16(
            af[mi], bv[ni], acc[mi][ni], 0, 0, 0);
    if (doRS && wn == 0) {
      #pragma unroll
      for (int i = 0; i < 4; ++i)
        accS[i] = __builtin_amdgcn_mfma_f32_16x16x32_bf16(
            af[i], gv, accS[i], 0, 0, 0);
    }
    __builtin_amdgcn_s_setprio(0);
    __builtin_amdgcn_sched_barrier(0);
    if (tt + 1 < nT) {
      if (tt + 3 < nT) {
        asm volatile("s_waitcnt vmcnt(8)" ::: "memory");
      } else {
        asm volatile("s_waitcnt vmcnt(0)" ::: "memory");
      }
      __builtin_amdgcn_s_barrier();
      __builtin_amdgcn_sched_barrier(0);
    }
    cur ^= 1;
  }

  if (doRS && wn == 0 && lr < 2) {
    float* dst = ((lr == 0) ? denp : alp) + (size_t)kc * M + m0 + wm * 64;
    #pragma unroll
    for (int i = 0; i < 4; ++i)
      #pragma unroll
      for (int v = 0; v < 4; ++v)
        dst[i * 16 + lk * 4 + v] = accS[i][v];
  }

  float* C = (kc == 0) ? C0 : Cext;
  // C/D layout: col = lane&15, row = (lane>>4)*4 + reg   [m89-verified]
  float* Cw = C + (size_t)(m0 + wm * 64 + lk * 4) * DD + n0 + wn * 128 + lr;
  #pragma unroll
  for (int mi = 0; mi < 4; ++mi)
    #pragma unroll
    for (int ni = 0; ni < 8; ++ni)
      #pragma unroll
      for (int v = 0; v < 4; ++v)
        Cw[(size_t)(mi * 16 + v) * DD + ni * 16] = acc[mi][ni][v];
}

// ---------------- row stats (mobius_matvec scalars + gamma) ----------------
__global__ __launch_bounds__(256) void rowstats(const float* __restrict__ X,
                                                const float* __restrict__ mx,
                                                float* __restrict__ fg,
                                                u16* __restrict__ g1bf) {
  const int row  = (blockIdx.x << 2) + (threadIdx.x >> 6);
  const int lane = threadIdx.x & 63;
  const float* xr = X  + (size_t)row * DD + lane * 8;
  const float* mr = mx + (size_t)row * DD + lane * 8;
  float4 a0 = *(const float4*)xr, a1 = *(const float4*)(xr + 4);
  float4 b0 = *(const float4*)mr, b1 = *(const float4*)(mr + 4);
  float sx = a0.x*a0.x + a0.y*a0.y + a0.z*a0.z + a0.w*a0.w
           + a1.x*a1.x + a1.y*a1.y + a1.z*a1.z + a1.w*a1.w;
  float sm = b0.x*b0.x + b0.y*b0.y + b0.z*b0.z + b0.w*b0.w
           + b1.x*b1.x + b1.y*b1.y + b1.z*b1.z + b1.w*b1.w;
  sx = wred(sx); sm = wred(sm);
  if (lane == 0) {
    float xn  = sqrtf(fmaxf(sx, 1e-20f));
    float mxn = sqrtf(fmaxf(sm, 1e-20f));
    float at  = atanhf(fminf(xn, 0.9999999f));
    float t_  = tanhf(mxn / xn * at);
    bool  z   = (mxn <= 1e-10f);
    float factor = z ? 0.f : t_ / mxn;
    float xwsq   = z ? 0.f : t_ * t_ * (sm / (mxn * mxn));
    float g = 2.f / (1.f - xwsq);          // kappa = -1
    g = fmaxf(g, 1e-15f);
    fg[row] = factor * g;
    g1bf[row] = f2bf(g - 1.f);
  }
}

// ---------------- B_T build: Bt[d][j] = fg[j]*mx[j][d], 16B-slot swizzled --
__global__ __launch_bounds__(256) void build_bt(const float* __restrict__ mx,
                                                const float* __restrict__ fg,
                                                u16* __restrict__ Bt) {
  __shared__ float tile[64][65];
  const int j0 = blockIdx.x * 64, d0 = blockIdx.y * 64;
  const int t = threadIdx.x;
  const int r0 = t >> 4, c4 = (t & 15) * 4;
  #pragma unroll
  for (int p = 0; p < 4; ++p) {
    const int r = r0 + p * 16;
    const float s = fg[j0 + r];
    float4 v = *(const float4*)&mx[(size_t)(j0 + r) * DD + d0 + c4];
    tile[r][c4 + 0] = s * v.x; tile[r][c4 + 1] = s * v.y;
    tile[r][c4 + 2] = s * v.z; tile[r][c4 + 3] = s * v.w;
  }
  __syncthreads();
  const int dr = t >> 2, jc = (t & 3) * 16;
  u32 r[8];
  #pragma unroll
  for (int u = 0; u < 8; ++u) {
    float lo = tile[jc + 2 * u][dr];
    float hi = tile[jc + 2 * u + 1][dr];
    r[u] = (u32)f2bf(lo) | ((u32)f2bf(hi) << 16);
  }
  const int s0 = (jc >> 3) & 3;
  const int px = dr & 3;
  u32* rowp = (u32*)(Bt + (size_t)(d0 + dr) * NR + j0 + (jc & 32));
  *(uint4*)(rowp + ((s0 ^ px) * 4))       = *(const uint4*)&r[0];
  *(uint4*)(rowp + (((s0 + 1) ^ px) * 4)) = *(const uint4*)&r[4];
}

// ---------------- epilogue (sums 2 split-K partials + den/al partials) -----
__global__ __launch_bounds__(256) void epilogue(const float* __restrict__ P0,
                                                const float* __restrict__ P1,
                                                const float* __restrict__ denp,
                                                const float* __restrict__ alp,
                                                float* __restrict__ out) {
  const int row  = (blockIdx.x << 2) + (threadIdx.x >> 6);
  const int lane = threadIdx.x & 63;
  const size_t ro = (size_t)row * DD + lane * 8;
  float4 n0 = *(const float4*)(P0 + ro), n1 = *(const float4*)(P0 + ro + 4);
  float4 a = *(const float4*)(P1 + ro), b = *(const float4*)(P1 + ro + 4);
  n0.x += a.x; n0.y += a.y; n0.z += a.z; n0.w += a.w;
  n1.x += b.x; n1.y += b.y; n1.z += b.z; n1.w += b.w;

  float de    = denp[row] + denp[NR + row];
  float alpha = alp[row]  + alp[NR + row];
  de = (de >= 0.f ? 1.f : -1.f) * fmaxf(fabsf(de), 1e-10f);

  float v[8] = {n0.x / de, n0.y / de, n0.z / de, n0.w / de,
                n1.x / de, n1.y / de, n1.z / de, n1.w / de};
  float sq = 0.f;
  #pragma unroll
  for (int j = 0; j < 8; ++j) sq += v[j] * v[j];
  sq = wred(sq);
  float s1 = 1.f + sqrtf(fmaxf(1.f - sq, 1e-10f));     // 1+sqrt(max(1+k*sq,EPS))
  float an = sqrtf(fmaxf(sq / (s1 * s1), 1e-20f));     // ||a_mean|| clamped
  float t2 = tanhf(alpha * atanhf(fminf(an, 0.9999999f)));
  float f2 = t2 / (an * s1);                           // res = f2 * v
  float xsq = f2 * f2 * sq;
  float xn = sqrtf(fmaxf(xsq, 1e-20f));
  float lf = atanhf(fminf(xn, 0.9999999f)) / xn;       // logmap0 scale
  float u[8]; float us = 0.f;
  #pragma unroll
  for (int j = 0; j < 8; ++j) {
    u[j] = fmaxf(lf * f2 * v[j], 0.f);                 // relu(log0)
    us += u[j] * u[j];
  }
  us = wred(us);
  float un = sqrtf(fmaxf(us, 1e-20f));
  float ef = tanhf(un) / un;                           // expmap0 scale
  float o[8];
  #pragma unroll
  for (int j = 0; j < 8; ++j) o[j] = ef * u[j];
  float* orow = out + (size_t)row * DD + lane * 8;
  *(float4*)orow       = (float4){o[0], o[1], o[2], o[3]};
  *(float4*)(orow + 4) = (float4){o[4], o[5], o[6], o[7]};
}

// ---------------- launch ----------------
extern "C" void kernel_launch(void* const* d_in, const int* in_sizes, int n_in,
                              void* d_out, int out_size, void* d_ws, size_t ws_size,
                              hipStream_t stream) {
  const float* X = (const float*)d_in[0];
  const float* A = (const float*)d_in[1];
  const float* W = (const float*)d_in[2];
  float* out = (float*)d_out;
  char* ws = (char*)d_ws;

  float* mx   = (float*)(ws);                 // 16777216 B (= P0, nom)
  float* P1   = (float*)(ws + 16777216);      // 16777216 B -> 33554432
  u16*   Bt   = (u16*)(ws + 33554432);        // 8388608 B  -> 41943040
  u16*   Wt   = (u16*)(ws + 41943040);        // 524288 B   -> 42467328
  float* fg   = (float*)(ws + 42467328);      // 32768 B    -> 42500096
  u16*   g1bf = (u16*)(ws + 42500096);        // 16384 B    -> 42516480
  float* denp = (float*)(ws + 42516480);      // 2*32768 B  -> 42582016
  float* alp  = (float*)(ws + 42582016);      // 2*32768 B  -> 42647552

  conv_wt<<<128, 256, 0, stream>>>(W, Wt);
  // mx = X @ W : M=8192, K=512, grid 64x2, no split
  gemm_ph<0><<<128, 256, 0, stream>>>(X, Wt, g1bf, mx, mx, denp, alp,
                                      NR, DD, DD, 1);
  rowstats<<<2048, 256, 0, stream>>>(X, mx, fg, g1bf);
  build_bt<<<dim3(128, 8), 256, 0, stream>>>(mx, fg, Bt);
  // nom = A @ Bt^T : split-K=2, grid 64x2x2 = 256, fused denom/alpha
  gemm_ph<1><<<256, 256, 0, stream>>>(A, Bt, g1bf, mx, P1, denp, alp,
                                      NR, NR, NR / 2, 2);
  epilogue<<<2048, 256, 0, stream>>>(mx, P1, denp, alp, out);
}

// Round 9
// 178.235 us; speedup vs baseline: 1.3082x; 1.3082x over previous
//
#include <hip/hip_runtime.h>

// KappaGCN layer on MI355X. KAPPA=-1, N=8192, D=512.
// Round 9: R8's regression was a launch-geometry bug: split-K=2 made the
// grid 256 = exactly 1 block/CU (occupancy 11%), so the second resident
// block never existed; and nt=bid&1 put A-sharing siblings on different
// XCDs (A fetched twice, FETCH 270MB). Now split-K=4 -> grid 512 = 2
// blocks/CU; decode bit0=mt-low, bits1-2=kc (XCD pair), bit3=nt (same XCD
// as sibling: bids differ by 8), bits4+=mt-high. Kernel body unchanged
// (2-phase split, counted vmcnt(8), setprio, fused denom/alpha MFMAs).

#define NR 8192
#define DD 512

typedef unsigned int u32;
typedef unsigned short u16;
typedef __attribute__((ext_vector_type(8))) short bf16x8;
typedef __attribute__((ext_vector_type(4))) float f32x4;

__device__ __forceinline__ u16 f2bf(float f) {
  u32 u = __float_as_uint(f);
  u32 r = u + 0x7FFFu + ((u >> 16) & 1u);   // round-to-nearest-even
  return (u16)(r >> 16);
}

__device__ __forceinline__ u32 cvtpk(float lo, float hi) {
  u32 r;
  asm("v_cvt_pk_bf16_f32 %0, %1, %2" : "=v"(r) : "v"(lo), "v"(hi));
  return r;
}

__device__ __forceinline__ void gload16(const void* g, void* l) {
  __builtin_amdgcn_global_load_lds(
      (const __attribute__((address_space(1))) u32*)g,
      (__attribute__((address_space(3))) u32*)l, 16, 0, 0);
}

__device__ __forceinline__ float wred(float v) {
  #pragma unroll
  for (int off = 32; off; off >>= 1) v += __shfl_xor(v, off, 64);
  return v;
}

// W [K=512][N=512] fp32 -> Wt [N][K] bf16, 16B-slot swizzled per 32-k chunk
__global__ __launch_bounds__(256) void conv_wt(const float* __restrict__ W,
                                               u16* __restrict__ Wt) {
  const int idx = blockIdx.x * 256 + threadIdx.x;  // 0..32767
  const int n  = idx >> 6;
  const int k0 = (idx & 63) * 8;
  u32 r[4];
  #pragma unroll
  for (int j = 0; j < 4; ++j) {
    float lo = W[(size_t)(k0 + 2*j    ) * DD + n];
    float hi = W[(size_t)(k0 + 2*j + 1) * DD + n];
    r[j] = (u32)f2bf(lo) | ((u32)f2bf(hi) << 16);
  }
  const int dst = n * DD + ((idx & 63) >> 2) * 32 + (((idx & 3) ^ (n & 3)) * 8);
  *(uint4*)(Wt + dst) = *(const uint4*)r;
}

// ---------------- GEMM: C[M][512] = Af[M][K](fp32) * Bt[512][K](bf16,swz) --
// 128x256 tile, BK=32, 4 waves (2x2), wave tile 64x128 (4x8 frags 16x16x32).
// Per K-step: Ph0 {16 frag reads, prio MFMA x16}, barrier,
// Ph1 {stage 8 gload_lds, prio MFMA x16 + dosum}, vmcnt(8), barrier.
template <int DOSUM>
__global__ __launch_bounds__(256, 2) void gemm_ph(
    const float* __restrict__ Af, const u16* __restrict__ Bt,
    const u16* __restrict__ g1bf,
    float* __restrict__ C0, float* __restrict__ Cext,
    float* __restrict__ denp, float* __restrict__ alp,
    int M, int K, int kchunk, int nkc) {
  __shared__ __align__(16) float ldsA[2][4096];   // [128][32] f32, slot^row&7
  __shared__ __align__(16) u16   ldsB[2][8192];   // [256][32] bf16, slot^row&3
  __shared__ __align__(16) u16   ldsG[4096];      // g1bf chunk (DOSUM)

  // decode: b0 = mt-low, b1-b2 = kc (XCD pair owns one kc), b3 = nt
  // (A-sharing nt-siblings differ by 8 -> same XCD L2), b4+ = mt-high.
  const int bid = blockIdx.x;
  int mt, nt, kc;
  if (nkc == 4) {
    kc = (bid >> 1) & 3;
    nt = (bid >> 3) & 1;
    mt = ((bid >> 4) << 1) | (bid & 1);
  } else {
    kc = 0;
    nt = bid & 1;
    mt = bid >> 1;
  }

  const int t = threadIdx.x;
  const int lane = t & 63, w = t >> 6;
  const int wm = w >> 1, wn = w & 1;              // 2 x 2 waves
  const int m0 = mt * 128, n0 = nt * 256;
  const int kbeg = kc * kchunk;
  const int lr = lane & 15, lk = lane >> 4, lx = lr & 7;
  const bool doRS = DOSUM && (nt == 0);

  // A staging: thread t covers rows (t>>3)+32j, phys slot t&7;
  // source fetches logical slot (t&7)^(row&7) (pre-swizzle).
  const int scol = ((t & 7) ^ ((t >> 3) & 7)) << 2;   // floats
  const float* gA0 = Af + (size_t)(m0 + (t >> 3)) * K + kbeg + scol;
  // B staging (verbatim; Bt pre-swizzled in global): rows (t>>2)+64j
  const u16* gB = Bt + (size_t)(n0 + (t >> 2)) * K + kbeg + (t & 3) * 8;

  auto stage = [&](int buf, int kt) {
    const int ko = kt * 32;
    #pragma unroll
    for (int j = 0; j < 4; ++j)
      gload16(gA0 + ko + (size_t)j * 32 * K, &ldsA[buf][t * 4 + j * 1024]);
    #pragma unroll
    for (int j = 0; j < 4; ++j)
      gload16(gB + ko + (size_t)j * 64 * K, &ldsB[buf][t * 8 + j * 2048]);
  };

  f32x4 acc[4][8];
  #pragma unroll
  for (int i = 0; i < 4; ++i)
    #pragma unroll
    for (int j = 0; j < 8; ++j) acc[i][j] = (f32x4){0.f, 0.f, 0.f, 0.f};
  f32x4 accS[4];
  #pragma unroll
  for (int i = 0; i < 4; ++i) accS[i] = (f32x4){0.f, 0.f, 0.f, 0.f};

  const int nT = kchunk / 32;

  // ---- prologue: ldsG + tiles 0,1; wait tile 0 only ----
  if (doRS) {
    #pragma unroll
    for (int j = 0; j < 2; ++j)
      gload16(g1bf + kbeg + t * 8 + j * 2048, &ldsG[t * 8 + j * 2048]);
  }
  stage(0, 0);
  stage(1, 1);
  asm volatile("s_waitcnt vmcnt(8)" ::: "memory");
  __builtin_amdgcn_s_barrier();
  __builtin_amdgcn_sched_barrier(0);

  int cur = 0;
  for (int tt = 0; tt < nT; ++tt) {
    // ---- Ph0: all frag reads from buf[cur], then first MFMA cluster ----
    bf16x8 af[4], bv[8];
    #pragma unroll
    for (int i = 0; i < 4; ++i) {
      const int rbase = (wm * 64 + i * 16 + lr) * 32;
      f32x4 lo = *(const f32x4*)&ldsA[cur][rbase + (((2*lk    ) ^ lx) << 2)];
      f32x4 hi = *(const f32x4*)&ldsA[cur][rbase + (((2*lk + 1) ^ lx) << 2)];
      union { u32 u[4]; bf16x8 v; } pk;
      pk.u[0] = cvtpk(lo.x, lo.y); pk.u[1] = cvtpk(lo.z, lo.w);
      pk.u[2] = cvtpk(hi.x, hi.y); pk.u[3] = cvtpk(hi.z, hi.w);
      af[i] = pk.v;
    }
    #pragma unroll
    for (int i = 0; i < 8; ++i) {
      const int rb = (wn * 128 + i * 16 + lr) * 32 + ((lk ^ (lr & 3)) << 3);
      bv[i] = *(const bf16x8*)&ldsB[cur][rb];
    }
    __builtin_amdgcn_s_setprio(1);
    #pragma unroll
    for (int mi = 0; mi < 4; ++mi)
      #pragma unroll
      for (int ni = 0; ni < 4; ++ni)
        acc[mi][ni] = __builtin_amdgcn_mfma_f32_16x16x32_bf16(
            af[mi], bv[ni], acc[mi][ni], 0, 0, 0);
    __builtin_amdgcn_s_setprio(0);
    // all this wave's reads of buf[cur] done before anyone stages into it
    asm volatile("s_waitcnt lgkmcnt(0)" ::: "memory");
    __builtin_amdgcn_sched_barrier(0);
    __builtin_amdgcn_s_barrier();
    __builtin_amdgcn_sched_barrier(0);
    // ---- Ph1: stage tt+2 into buf[cur], second MFMA cluster ----
    if (tt + 2 < nT) stage(cur, tt + 2);
    bf16x8 gv;
    if (doRS && wn == 0) {
      if (lr == 0) {
        gv = *(const bf16x8*)&ldsG[tt * 32 + lk * 8];
      } else {
        const short s = (lr == 1) ? (short)0x3F80 : (short)0;
        gv = (bf16x8){s, s, s, s, s, s, s, s};
      }
    }
    __builtin_amdgcn_sched_barrier(0);
    __builtin_amdgcn_s_setprio(1);
    #pragma unroll
    for (int mi = 0; mi < 4; ++mi)
      #pragma unroll
      for (int ni = 4; ni < 8; ++ni)
        acc[mi][ni] = __builtin_amdgcn_mfma_f32_16x16x32_bf16(
            af[mi], bv[ni], acc[mi][ni], 0, 0, 0);
    if (doRS && wn == 0) {
      #pragma unroll
      for (int i = 0; i < 4; ++i)
        accS[i] = __builtin_amdgcn_mfma_f32_16x16x32_bf16(
            af[i], gv, accS[i], 0, 0, 0);
    }
    __builtin_amdgcn_s_setprio(0);
    __builtin_amdgcn_sched_barrier(0);
    if (tt + 1 < nT) {
      if (tt + 3 < nT) {
        asm volatile("s_waitcnt vmcnt(8)" ::: "memory");
      } else {
        asm volatile("s_waitcnt vmcnt(0)" ::: "memory");
      }
      __builtin_amdgcn_s_barrier();
      __builtin_amdgcn_sched_barrier(0);
    }
    cur ^= 1;
  }

  if (doRS && wn == 0 && lr < 2) {
    float* dst = ((lr == 0) ? denp : alp) + (size_t)kc * M + m0 + wm * 64;
    #pragma unroll
    for (int i = 0; i < 4; ++i)
      #pragma unroll
      for (int v = 0; v < 4; ++v)
        dst[i * 16 + lk * 4 + v] = accS[i][v];
  }

  float* C = (kc == 0) ? C0 : (Cext + (size_t)(kc - 1) * M * DD);
  // C/D layout: col = lane&15, row = (lane>>4)*4 + reg   [m89-verified]
  float* Cw = C + (size_t)(m0 + wm * 64 + lk * 4) * DD + n0 + wn * 128 + lr;
  #pragma unroll
  for (int mi = 0; mi < 4; ++mi)
    #pragma unroll
    for (int ni = 0; ni < 8; ++ni)
      #pragma unroll
      for (int v = 0; v < 4; ++v)
        Cw[(size_t)(mi * 16 + v) * DD + ni * 16] = acc[mi][ni][v];
}

// ---------------- row stats (mobius_matvec scalars + gamma) ----------------
__global__ __launch_bounds__(256) void rowstats(const float* __restrict__ X,
                                                const float* __restrict__ mx,
                                                float* __restrict__ fg,
                                                u16* __restrict__ g1bf) {
  const int row  = (blockIdx.x << 2) + (threadIdx.x >> 6);
  const int lane = threadIdx.x & 63;
  const float* xr = X  + (size_t)row * DD + lane * 8;
  const float* mr = mx + (size_t)row * DD + lane * 8;
  float4 a0 = *(const float4*)xr, a1 = *(const float4*)(xr + 4);
  float4 b0 = *(const float4*)mr, b1 = *(const float4*)(mr + 4);
  float sx = a0.x*a0.x + a0.y*a0.y + a0.z*a0.z + a0.w*a0.w
           + a1.x*a1.x + a1.y*a1.y + a1.z*a1.z + a1.w*a1.w;
  float sm = b0.x*b0.x + b0.y*b0.y + b0.z*b0.z + b0.w*b0.w
           + b1.x*b1.x + b1.y*b1.y + b1.z*b1.z + b1.w*b1.w;
  sx = wred(sx); sm = wred(sm);
  if (lane == 0) {
    float xn  = sqrtf(fmaxf(sx, 1e-20f));
    float mxn = sqrtf(fmaxf(sm, 1e-20f));
    float at  = atanhf(fminf(xn, 0.9999999f));
    float t_  = tanhf(mxn / xn * at);
    bool  z   = (mxn <= 1e-10f);
    float factor = z ? 0.f : t_ / mxn;
    float xwsq   = z ? 0.f : t_ * t_ * (sm / (mxn * mxn));
    float g = 2.f / (1.f - xwsq);          // kappa = -1
    g = fmaxf(g, 1e-15f);
    fg[row] = factor * g;
    g1bf[row] = f2bf(g - 1.f);
  }
}

// ---------------- B_T build: Bt[d][j] = fg[j]*mx[j][d], 16B-slot swizzled --
__global__ __launch_bounds__(256) void build_bt(const float* __restrict__ mx,
                                                const float* __restrict__ fg,
                                                u16* __restrict__ Bt) {
  __shared__ float tile[64][65];
  const int j0 = blockIdx.x * 64, d0 = blockIdx.y * 64;
  const int t = threadIdx.x;
  const int r0 = t >> 4, c4 = (t & 15) * 4;
  #pragma unroll
  for (int p = 0; p < 4; ++p) {
    const int r = r0 + p * 16;
    const float s = fg[j0 + r];
    float4 v = *(const float4*)&mx[(size_t)(j0 + r) * DD + d0 + c4];
    tile[r][c4 + 0] = s * v.x; tile[r][c4 + 1] = s * v.y;
    tile[r][c4 + 2] = s * v.z; tile[r][c4 + 3] = s * v.w;
  }
  __syncthreads();
  const int dr = t >> 2, jc = (t & 3) * 16;
  u32 r[8];
  #pragma unroll
  for (int u = 0; u < 8; ++u) {
    float lo = tile[jc + 2 * u][dr];
    float hi = tile[jc + 2 * u + 1][dr];
    r[u] = (u32)f2bf(lo) | ((u32)f2bf(hi) << 16);
  }
  const int s0 = (jc >> 3) & 3;
  const int px = dr & 3;
  u32* rowp = (u32*)(Bt + (size_t)(d0 + dr) * NR + j0 + (jc & 32));
  *(uint4*)(rowp + ((s0 ^ px) * 4))       = *(const uint4*)&r[0];
  *(uint4*)(rowp + (((s0 + 1) ^ px) * 4)) = *(const uint4*)&r[4];
}

// ---------------- epilogue (sums 4 split-K partials + den/al partials) -----
__global__ __launch_bounds__(256) void epilogue(const float* __restrict__ P0,
                                                const float* __restrict__ P1,
                                                const float* __restrict__ P2,
                                                const float* __restrict__ P3,
                                                const float* __restrict__ denp,
                                                const float* __restrict__ alp,
                                                float* __restrict__ out) {
  const int row  = (blockIdx.x << 2) + (threadIdx.x >> 6);
  const int lane = threadIdx.x & 63;
  const size_t ro = (size_t)row * DD + lane * 8;
  float4 n0 = *(const float4*)(P0 + ro), n1 = *(const float4*)(P0 + ro + 4);
  float4 a, b;
  a = *(const float4*)(P1 + ro); b = *(const float4*)(P1 + ro + 4);
  n0.x += a.x; n0.y += a.y; n0.z += a.z; n0.w += a.w;
  n1.x += b.x; n1.y += b.y; n1.z += b.z; n1.w += b.w;
  a = *(const float4*)(P2 + ro); b = *(const float4*)(P2 + ro + 4);
  n0.x += a.x; n0.y += a.y; n0.z += a.z; n0.w += a.w;
  n1.x += b.x; n1.y += b.y; n1.z += b.z; n1.w += b.w;
  a = *(const float4*)(P3 + ro); b = *(const float4*)(P3 + ro + 4);
  n0.x += a.x; n0.y += a.y; n0.z += a.z; n0.w += a.w;
  n1.x += b.x; n1.y += b.y; n1.z += b.z; n1.w += b.w;

  float de = 0.f, alpha = 0.f;
  #pragma unroll
  for (int kc = 0; kc < 4; ++kc) {
    de    += denp[kc * NR + row];
    alpha += alp [kc * NR + row];
  }
  de = (de >= 0.f ? 1.f : -1.f) * fmaxf(fabsf(de), 1e-10f);

  float v[8] = {n0.x / de, n0.y / de, n0.z / de, n0.w / de,
                n1.x / de, n1.y / de, n1.z / de, n1.w / de};
  float sq = 0.f;
  #pragma unroll
  for (int j = 0; j < 8; ++j) sq += v[j] * v[j];
  sq = wred(sq);
  float s1 = 1.f + sqrtf(fmaxf(1.f - sq, 1e-10f));     // 1+sqrt(max(1+k*sq,EPS))
  float an = sqrtf(fmaxf(sq / (s1 * s1), 1e-20f));     // ||a_mean|| clamped
  float t2 = tanhf(alpha * atanhf(fminf(an, 0.9999999f)));
  float f2 = t2 / (an * s1);                           // res = f2 * v
  float xsq = f2 * f2 * sq;
  float xn = sqrtf(fmaxf(xsq, 1e-20f));
  float lf = atanhf(fminf(xn, 0.9999999f)) / xn;       // logmap0 scale
  float u[8]; float us = 0.f;
  #pragma unroll
  for (int j = 0; j < 8; ++j) {
    u[j] = fmaxf(lf * f2 * v[j], 0.f);                 // relu(log0)
    us += u[j] * u[j];
  }
  us = wred(us);
  float un = sqrtf(fmaxf(us, 1e-20f));
  float ef = tanhf(un) / un;                           // expmap0 scale
  float o[8];
  #pragma unroll
  for (int j = 0; j < 8; ++j) o[j] = ef * u[j];
  float* orow = out + (size_t)row * DD + lane * 8;
  *(float4*)orow       = (float4){o[0], o[1], o[2], o[3]};
  *(float4*)(orow + 4) = (float4){o[4], o[5], o[6], o[7]};
}

// ---------------- launch ----------------
extern "C" void kernel_launch(void* const* d_in, const int* in_sizes, int n_in,
                              void* d_out, int out_size, void* d_ws, size_t ws_size,
                              hipStream_t stream) {
  const float* X = (const float*)d_in[0];
  const float* A = (const float*)d_in[1];
  const float* W = (const float*)d_in[2];
  float* out = (float*)d_out;
  char* ws = (char*)d_ws;

  float* mx   = (float*)(ws);                 // 16777216 B (= P0, nom)
  float* Pext = (float*)(ws + 16777216);      // 3 x 16777216 B -> 67108864
  u16*   Bt   = (u16*)(ws + 67108864);        // 8388608 B  -> 75497472
  u16*   Wt   = (u16*)(ws + 75497472);        // 524288 B   -> 76021760
  float* fg   = (float*)(ws + 76021760);      // 32768 B    -> 76054528
  u16*   g1bf = (u16*)(ws + 76054528);        // 16384 B    -> 76070912
  float* denp = (float*)(ws + 76087296);      // 4*32768 B  -> 76218368
  float* alp  = (float*)(ws + 76218368);      // 4*32768 B  -> 76349440

  const size_t MNf = (size_t)NR * DD;         // floats per partial

  conv_wt<<<128, 256, 0, stream>>>(W, Wt);
  // mx = X @ W : M=8192, K=512, grid 64x2, no split
  gemm_ph<0><<<128, 256, 0, stream>>>(X, Wt, g1bf, mx, mx, denp, alp,
                                      NR, DD, DD, 1);
  rowstats<<<2048, 256, 0, stream>>>(X, mx, fg, g1bf);
  build_bt<<<dim3(128, 8), 256, 0, stream>>>(mx, fg, Bt);
  // nom = A @ Bt^T : split-K=4, grid 64x2x4 = 512 = 2 blocks/CU
  gemm_ph<1><<<512, 256, 0, stream>>>(A, Bt, g1bf, mx, Pext, denp, alp,
                                      NR, NR, NR / 4, 4);
  epilogue<<<2048, 256, 0, stream>>>(mx, Pext, Pext + MNf, Pext + 2 * MNf,
                                     denp, alp, out);
}